// Round 6
// baseline (937.411 us; speedup 1.0000x reference)
//
#include <hip/hip_runtime.h>

// Problem constants
#define N_USER  60000
#define N_ITEM  40000
#define NN      100000          // total nodes
#define NNZ_E   1600000         // edges per relation
#define BB      16384           // batch pairs
#define ND      6400000         // NN * 64
#define ND4     1600000         // NN * 16 (float4 elements)
#define NCHUNK  6250            // NN / 16 row-chunks for dense
#define NBUCK   196             // row buckets of 512 rows
#define BUCK_CAP 9216           // fixed bucket capacity
#define BUCKTOT (NBUCK * BUCK_CAP)
#define BINB    196             // bin blocks per relation
#define EPB     8192            // edges per bin block (LDS-staged)
#define DGRID   1024            // standalone dense grid (4 blocks/CU at 33.8KB LDS)
#define DBLK    512             // dense blocks inside merged sd dispatch

typedef __attribute__((ext_vector_type(8))) short bf16x8;
typedef __attribute__((ext_vector_type(8))) unsigned short u16x8;
typedef __attribute__((ext_vector_type(4))) float f32x4;

__device__ __forceinline__ float tanh_fast(float x) {
    x = fminf(fmaxf(x, -15.f), 15.f);
    float e = __expf(2.f * x);
    return (e - 1.f) / (e + 1.f);
}

__device__ __forceinline__ float bcast(float x, int k) {
    return __int_as_float(__builtin_amdgcn_readlane(__float_as_int(x), k));
}

__device__ __forceinline__ unsigned short f2bf(float f) {
    unsigned u = __float_as_uint(f);
    u += 0x7FFFu + ((u >> 16) & 1u);       // RNE
    return (unsigned short)(u >> 16);
}
__device__ __forceinline__ float bf2f(unsigned short s) {
    return __uint_as_float(((unsigned)s) << 16);
}

// frag-order index for B-operand element (k, n) of a 64x64 matrix
__device__ __forceinline__ int widx(int k, int n) {
    return ((((n >> 4) * 2 + (k >> 5)) * 4 + ((k >> 3) & 3)) * 16 + (n & 15)) * 8 + (k & 7);
}

// ---------------------------------------------------------------------------
// prep: frag-order bf16 att weights (2 layers x 3 rels) + CURS/ATT init.
// Runs once, before ib_kernel (so bin's atomic reservations see valid CURS).
__global__ __launch_bounds__(256) void prep_kernel(
    const float* __restrict__ attM_W, const float* __restrict__ attA_W,
    const float* __restrict__ attT_W, ushort* __restrict__ WF,
    int* __restrict__ CURS, float* __restrict__ attsum)
{
    int b = blockIdx.x;
    if (b == 6) {
        for (int i = threadIdx.x; i < 3 * NBUCK; i += 256)
            CURS[i] = (i % NBUCK) * BUCK_CAP;
        if (threadIdx.x < 16) attsum[threadIdx.x] = 0.f;
        return;
    }
    int l = b / 3, q = b % 3;
    const float* src = ((q == 0) ? attM_W : ((q == 1) ? attA_W : attT_W)) + (size_t)l * 4096;
    ushort* dst = WF + ((size_t)l * 3 + q) * 4096;
    for (int i = threadIdx.x; i < 4096; i += 256) {
        int k = i >> 6, n = i & 63;
        dst[widx(k, n)] = f2bf(src[i]);
    }
}

// ---------------------------------------------------------------------------
// ib: merged [bin | init]. Blocks 0..3*BINB-1 run the proven bin v4 body;
// the remaining 3125 blocks stream init (fs/XB). No shared data between the
// two paths; block-uniform branch, so bin's barriers are safe.
__global__ __launch_bounds__(512) void ib_kernel(
    const int* __restrict__ rows0, const int* __restrict__ cols0, const float* __restrict__ vals0,
    const int* __restrict__ rows1, const int* __restrict__ cols1, const float* __restrict__ vals1,
    const int* __restrict__ rows2, const int* __restrict__ cols2, const float* __restrict__ vals2,
    int* __restrict__ CURS, int2* __restrict__ ECV,
    const float4* __restrict__ u, const float4* __restrict__ it,
    ushort* __restrict__ XB, float4* __restrict__ fs)
{
    __shared__ int2 sStage[EPB];            // 64 KB (bin path only)
    __shared__ int hW[8 * NBUCK];
    __shared__ int lOff[NBUCK], lEnd[NBUCK], lCur[NBUCK], gB[NBUCK];
    __shared__ int wt[4];

    if (blockIdx.x >= 3 * BINB) {
        // ---- init path: fs = concat fp32; XB = bf16(concat) ----
        int i = (blockIdx.x - 3 * BINB) * 512 + threadIdx.x;
        if (i < ND4) {
            float4 v = (i < N_USER * 16) ? u[i] : it[i - N_USER * 16];
            fs[i] = v;
            ushort4 b;
            b.x = f2bf(v.x); b.y = f2bf(v.y); b.z = f2bf(v.z); b.w = f2bf(v.w);
            ((ushort4*)XB)[i] = b;
        }
        return;
    }

    // ---- bin path (round-0 proven v4, verbatim) ----
    int rel = blockIdx.x / BINB;
    int blk = blockIdx.x % BINB;
    const int* rows; const int* cols; const float* vals;
    if (rel == 0) { rows = rows0; cols = cols0; vals = vals0; }
    else if (rel == 1) { rows = rows1; cols = cols1; vals = vals1; }
    else { rows = rows2; cols = cols2; vals = vals2; }
    long long* out = (long long*)(ECV + (size_t)rel * BUCKTOT);

    int t = threadIdx.x;
    int lane = t & 63, w = t >> 6;
    for (int i = t; i < 8 * NBUCK; i += 512) hW[i] = 0;
    __syncthreads();

    int base = blk * EPB;
    int myrow[16];
    #pragma unroll
    for (int j = 0; j < 16; ++j) {
        int idx = base + j * 512 + t;
        myrow[j] = (idx < NNZ_E) ? __builtin_nontemporal_load(&rows[idx]) : -1;
        if (myrow[j] >= 0) atomicAdd(&hW[w * NBUCK + (myrow[j] >> 9)], 1);
    }
    __syncthreads();
    if (t < 256) {
        int h = 0;
        if (t < NBUCK) {
            #pragma unroll
            for (int ww = 0; ww < 8; ++ww) h += hW[ww * NBUCK + t];
        }
        int sc = h;
        #pragma unroll
        for (int o = 1; o < 64; o <<= 1) {
            int u2 = __shfl_up(sc, o);
            if (lane >= o) sc += u2;
        }
        if (lane == 63) wt[w] = sc;
        __syncthreads();
        int woff = 0;
        #pragma unroll
        for (int ww = 0; ww < 4; ++ww) if (ww < w) woff += wt[ww];
        int excl = woff + sc - h;
        if (t < NBUCK) {
            lOff[t] = excl;
            lEnd[t] = excl + h;
            lCur[t] = excl;
            gB[t] = h ? atomicAdd(&CURS[rel * NBUCK + t], h) : 0;
        }
    } else {
        __syncthreads();
    }
    __syncthreads();
    #pragma unroll
    for (int j = 0; j < 16; ++j) {
        int idx = base + j * 512 + t;
        if (myrow[j] >= 0) {
            int c = __builtin_nontemporal_load(&cols[idx]);
            float v = __builtin_nontemporal_load(&vals[idx]);
            int b = myrow[j] >> 9;
            int pos = atomicAdd(&lCur[b], 1);
            int2 e;
            e.x = ((myrow[j] & 511) << 17) | c;
            e.y = __float_as_int(v);
            sStage[pos] = e;
        }
    }
    __syncthreads();
    for (int b = w; b < NBUCK; b += 8) {
        int s = lOff[b], e = lEnd[b];
        int gb = gB[b];
        int lim = (b + 1) * BUCK_CAP;
        for (int i = s + lane; i < e; i += 64) {
            int d = gb + (i - s);
            if (d < lim) {
                int2 ev = sStage[i];
                long long packed = (((long long)(unsigned)ev.y) << 32) | (unsigned)ev.x;
                __builtin_nontemporal_store(packed, &out[d]);
            }
        }
    }
}

// ---------------------------------------------------------------------------
// bsort v2 (unchanged, proven).
__global__ __launch_bounds__(512) void bsort_kernel(
    const int* __restrict__ CURS, int2* __restrict__ ECV,
    int* __restrict__ RPS, int* __restrict__ RPE)
{
    int rel = blockIdx.x / NBUCK;
    int b   = blockIdx.x % NBUCK;
    int start = b * BUCK_CAP;
    int cnt = CURS[rel * NBUCK + b] - start;
    if (cnt > BUCK_CAP) cnt = BUCK_CAP;
    int2* ecv = ECV + (size_t)rel * BUCKTOT;

    __shared__ int2 sStage[BUCK_CAP];
    __shared__ int sOff[512], sCnt[512];
    __shared__ int wt[8];
    int t = threadIdx.x;
    int lane = t & 63, w = t >> 6;
    sCnt[t] = 0;
    __syncthreads();
    int2 e[18];
    #pragma unroll
    for (int j = 0; j < 18; ++j) {
        int i = t + j * 512;
        if (i < cnt) {
            e[j] = ecv[start + i];
            atomicAdd(&sCnt[((unsigned)e[j].x) >> 17], 1);
        }
    }
    __syncthreads();
    int h = sCnt[t];
    int sc = h;
    #pragma unroll
    for (int o = 1; o < 64; o <<= 1) {
        int u = __shfl_up(sc, o);
        if (lane >= o) sc += u;
    }
    if (lane == 63) wt[w] = sc;
    __syncthreads();
    int woff = 0;
    #pragma unroll
    for (int ww = 0; ww < 8; ++ww) if (ww < w) woff += wt[ww];
    int excl = woff + sc - h;
    __syncthreads();
    sOff[t] = excl;
    sCnt[t] = excl;
    __syncthreads();
    #pragma unroll
    for (int j = 0; j < 18; ++j) {
        int i = t + j * 512;
        if (i < cnt) {
            int rl = ((unsigned)e[j].x) >> 17;
            int pos = atomicAdd(&sCnt[rl], 1);
            int2 o2; o2.x = e[j].x & 0x1FFFF; o2.y = e[j].y;
            sStage[pos] = o2;
        }
    }
    __syncthreads();
    for (int i = t; i < cnt; i += 512) ecv[start + i] = sStage[i];
    int row = b * 512 + t;
    if (row < NN) {
        RPS[rel * NN + row] = start + sOff[t];
        RPE[rel * NN + row] = start + sCnt[t];
    }
}

// ---------------------------------------------------------------------------
// spmm body: exact round-0 proven v5 (the only solid 55us-class kernel).
__device__ __forceinline__ void spmm_body(
    int t, int bid,
    const int* __restrict__ RPS, const int* __restrict__ RPE,
    const int2* __restrict__ ecv, const ushort* __restrict__ XB,
    ushort* __restrict__ G)
{
    int lane = t & 63;
    int wv = t >> 6;
    int dl = lane & 7;
    int r = bid * 32 + wv * 8 + (lane >> 3);
    int ea = RPS[r], eb = RPE[r];
    int cnt = eb - ea;
    int cm = cnt;
    cm = max(cm, __shfl_xor(cm, 8));
    cm = max(cm, __shfl_xor(cm, 16));
    cm = max(cm, __shfl_xor(cm, 32));
    u16x8 xo8 = *(const u16x8*)&XB[(size_t)r * 64 + 8 * dl];
    float s1[8] = {0.f, 0.f, 0.f, 0.f, 0.f, 0.f, 0.f, 0.f};
    float s2[8] = {0.f, 0.f, 0.f, 0.f, 0.f, 0.f, 0.f, 0.f};
    for (int base = 0; base < cm; base += 4) {
        float vv[4]; u16x8 xx[4];
        #pragma unroll
        for (int j = 0; j < 4; ++j) {
            int i = base + j;
            bool ok = i < cnt;
            int is = ea + (ok ? i : 0);
            int2 cv = ecv[is];
            vv[j] = ok ? __int_as_float(cv.y) : 0.f;
            xx[j] = *(const u16x8*)&XB[(size_t)cv.x * 64 + 8 * dl];
        }
        #pragma unroll
        for (int j = 0; j < 4; ++j) {
            float v = vv[j];
            #pragma unroll
            for (int d = 0; d < 8; ++d) {
                float x = bf2f(xx[j][d]);
                s1[d] += v * x;
                s2[d] += v * x * x;
            }
        }
    }
    u16x8 o1, o2;
    #pragma unroll
    for (int d = 0; d < 8; ++d) {
        o1[d] = f2bf(s1[d] + bf2f(xo8[d]));
        o2[d] = f2bf(s2[d]);
    }
    *(u16x8*)&G[(size_t)r * 128 + 8 * dl]      = o1;
    *(u16x8*)&G[(size_t)r * 128 + 64 + 8 * dl] = o2;
}

// ---------------------------------------------------------------------------
// dense body: round-0 proven inner loop verbatim; only change: attW read as
// pre-converted frag-order bf16 from global (WA, L1-hot 8KB) instead of LDS,
// cutting LDS to ~33.8 KB so 4 blocks/CU fit (and merged spmm blocks keep
// their full 16 waves/CU).
__device__ __forceinline__ void dense_body(
    int tid, int bid, int nblk,
    const ushort* __restrict__ G, ushort* __restrict__ Hout,
    const float* __restrict__ linW, const float* __restrict__ interW,
    const float* __restrict__ linb, const float* __restrict__ interb,
    const ushort* __restrict__ WA, const float* __restrict__ attb,
    const float* __restrict__ avec, float* __restrict__ attsum,
    short* sL, short* sI, float* sH,
    float* sBias, float* sAttb, float* sAvec)
{
    for (int i = tid; i < 4096; i += 256) {
        int k = i >> 6, n = i & 63, ix = widx(k, n);
        sL[ix] = (short)f2bf(linW[i]);
        sI[ix] = (short)f2bf(interW[i]);
    }
    if (tid < 64) {
        sBias[tid] = linb[tid] + interb[tid];
        sAttb[tid] = attb[tid];
        sAvec[tid] = avec[tid];
    }
    __syncthreads();

    const bf16x8* pL = (const bf16x8*)sL;
    const bf16x8* pI = (const bf16x8*)sI;
    const bf16x8* pW = (const bf16x8*)WA;

    int lane = tid & 63;
    int wv = tid >> 6;
    int nl = lane & 15;
    int q  = lane >> 4;
    float* myH = sH + wv * (16 * 65);
    int gw = bid * 4 + wv;
    int nw = nblk * 4;
    float att_acc = 0.f;

    for (int c = gw; c < NCHUNK; c += nw) {
        int r0 = c * 16;
        const bf16x8* gp = (const bf16x8*)(G + (size_t)(r0 + nl) * 128);
        bf16x8 Ah[2], Qh[2];
        Ah[0] = gp[q];         Ah[1] = gp[4 + q];
        Qh[0] = gp[8 + q];     Qh[1] = gp[12 + q];
        #pragma unroll
        for (int nt = 0; nt < 4; ++nt) {
            float b = sBias[nt * 16 + nl];
            f32x4 acc = {b, b, b, b};
            #pragma unroll
            for (int kh = 0; kh < 2; ++kh) {
                int f = ((nt * 2 + kh) * 4 + q) * 16 + nl;
                acc = __builtin_amdgcn_mfma_f32_16x16x32_bf16(Ah[kh], pL[f], acc, 0, 0, 0);
                acc = __builtin_amdgcn_mfma_f32_16x16x32_bf16(Qh[kh], pI[f], acc, 0, 0, 0);
            }
            #pragma unroll
            for (int reg = 0; reg < 4; ++reg) {
                int row = q * 4 + reg;
                Hout[(size_t)(r0 + row) * 64 + nt * 16 + nl] = f2bf(acc[reg]);
                myH[row * 65 + nt * 16 + nl] = acc[reg];
            }
        }
        bf16x8 Th[2];
        #pragma unroll
        for (int kh = 0; kh < 2; ++kh) {
            #pragma unroll
            for (int j = 0; j < 8; ++j)
                Th[kh][j] = (short)f2bf(myH[nl * 65 + kh * 32 + q * 8 + j]);
        }
        #pragma unroll
        for (int nt = 0; nt < 4; ++nt) {
            float b = sAttb[nt * 16 + nl];
            f32x4 acc = {b, b, b, b};
            #pragma unroll
            for (int kh = 0; kh < 2; ++kh) {
                int f = ((nt * 2 + kh) * 4 + q) * 16 + nl;
                acc = __builtin_amdgcn_mfma_f32_16x16x32_bf16(Th[kh], pW[f], acc, 0, 0, 0);
            }
            float av = sAvec[nt * 16 + nl];
            #pragma unroll
            for (int reg = 0; reg < 4; ++reg)
                att_acc += tanh_fast(acc[reg]) * av;
        }
    }
    #pragma unroll
    for (int o = 32; o >= 1; o >>= 1) att_acc += __shfl_xor(att_acc, o);
    if (lane == 0) atomicAdd(attsum, att_acc);
}

// ---------------------------------------------------------------------------
__global__ __launch_bounds__(256, 4) void spmm_kernel(
    const int* __restrict__ RPS, const int* __restrict__ RPE,
    const int2* __restrict__ ecv,
    const ushort* __restrict__ XB, ushort* __restrict__ G)
{
    spmm_body(threadIdx.x, blockIdx.x, RPS, RPE, ecv, XB, G);
}

__global__ __launch_bounds__(256, 4) void dense_kernel(
    const ushort* __restrict__ G, ushort* __restrict__ Hout,
    const float* __restrict__ linW, const float* __restrict__ interW,
    const float* __restrict__ linb, const float* __restrict__ interb,
    const ushort* __restrict__ WA, const float* __restrict__ attb,
    const float* __restrict__ avec, float* __restrict__ attsum)
{
    __shared__ short sL[4096], sI[4096];
    __shared__ float sH[4 * 16 * 65];
    __shared__ float sBias[64], sAttb[64], sAvec[64];
    dense_body(threadIdx.x, blockIdx.x, gridDim.x, G, Hout,
               linW, interW, linb, interb, WA, attb, avec, attsum,
               sL, sI, sH, sBias, sAttb, sAvec);
}

// merged: blocks 0..DBLK-1 run dense (reads Gin), blocks DBLK.. run spmm
// (writes Gout). Disjoint buffers, no cross-path synchronization —
// block-level co-scheduling only.
__global__ __launch_bounds__(256, 4) void sd_kernel(
    const ushort* __restrict__ Gin, ushort* __restrict__ Hout,
    const float* __restrict__ linW, const float* __restrict__ interW,
    const float* __restrict__ linb, const float* __restrict__ interb,
    const ushort* __restrict__ WA, const float* __restrict__ attb,
    const float* __restrict__ avec, float* __restrict__ attsum,
    const int* __restrict__ RPS, const int* __restrict__ RPE,
    const int2* __restrict__ ecv, const ushort* __restrict__ XB,
    ushort* __restrict__ Gout)
{
    __shared__ short sL[4096], sI[4096];
    __shared__ float sH[4 * 16 * 65];
    __shared__ float sBias[64], sAttb[64], sAvec[64];
    if (blockIdx.x < DBLK) {
        dense_body(threadIdx.x, blockIdx.x, DBLK, Gin, Hout,
                   linW, interW, linb, interb, WA, attb, avec, attsum,
                   sL, sI, sH, sBias, sAttb, sAvec);
    } else {
        spmm_body(threadIdx.x, blockIdx.x - DBLK, RPS, RPE, ecv, XB, Gout);
    }
}

// ---------------------------------------------------------------------------
// beta = softmax(attsum/NN); x = b0*hM + b1*hA + b2*hT (bf16 in, read-once
// nontemporal via u64); XB = bf16(x) (skipped last layer); fs = (fs+x)*scale
__global__ __launch_bounds__(256) void combine_kernel(
    const unsigned long long* __restrict__ hM,
    const unsigned long long* __restrict__ hA,
    const unsigned long long* __restrict__ hT,
    const float* __restrict__ attsum,
    ushort4* __restrict__ XB, float4* __restrict__ fs, float scale, int doXB)
{
    float w0 = attsum[0] * (1.f / NN);
    float w1 = attsum[1] * (1.f / NN);
    float w2 = attsum[2] * (1.f / NN);
    float m = fmaxf(w0, fmaxf(w1, w2));
    float e0 = __expf(w0 - m), e1 = __expf(w1 - m), e2 = __expf(w2 - m);
    float inv = 1.f / (e0 + e1 + e2);
    float b0 = e0 * inv, b1 = e1 * inv, b2 = e2 * inv;

    int i = blockIdx.x * 256 + threadIdx.x;
    if (i >= ND4) return;
    unsigned long long pm = __builtin_nontemporal_load(&hM[i]);
    unsigned long long pa = __builtin_nontemporal_load(&hA[i]);
    unsigned long long pt = __builtin_nontemporal_load(&hT[i]);
    float4 x;
    x.x = b0 * bf2f((unsigned short)pm)         + b1 * bf2f((unsigned short)pa)         + b2 * bf2f((unsigned short)pt);
    x.y = b0 * bf2f((unsigned short)(pm >> 16)) + b1 * bf2f((unsigned short)(pa >> 16)) + b2 * bf2f((unsigned short)(pt >> 16));
    x.z = b0 * bf2f((unsigned short)(pm >> 32)) + b1 * bf2f((unsigned short)(pa >> 32)) + b2 * bf2f((unsigned short)(pt >> 32));
    x.w = b0 * bf2f((unsigned short)(pm >> 48)) + b1 * bf2f((unsigned short)(pa >> 48)) + b2 * bf2f((unsigned short)(pt >> 48));
    if (doXB) {
        ushort4 bo;
        bo.x = f2bf(x.x); bo.y = f2bf(x.y); bo.z = f2bf(x.z); bo.w = f2bf(x.w);
        XB[i] = bo;
    }
    float4 f = fs[i];
    f.x = (f.x + x.x) * scale;
    f.y = (f.y + x.y) * scale;
    f.z = (f.z + x.z) * scale;
    f.w = (f.w + x.w) * scale;
    fs[i] = f;
}

// ---------------------------------------------------------------------------
__global__ __launch_bounds__(256) void mlp_kernel(
    const int* __restrict__ userIdx, const int* __restrict__ itemIdx,
    const float* __restrict__ fin,
    const float* __restrict__ W1, const float* __restrict__ b1,
    const float* __restrict__ W2, const float* __restrict__ b2,
    const float* __restrict__ W3, const float* __restrict__ b3,
    float* __restrict__ pred, float* __restrict__ userE, float* __restrict__ itemE)
{
    __shared__ float sW1[128 * 64];
    __shared__ float sW2[64 * 32];
    __shared__ float sW3[32];
    __shared__ float sb1[64];
    __shared__ float sb2[32];
    int tid = threadIdx.x;
    for (int i = tid; i < 8192; i += 256) sW1[i] = W1[i];
    for (int i = tid; i < 2048; i += 256) sW2[i] = W2[i];
    if (tid < 32) sW3[tid] = W3[tid];
    if (tid < 64) sb1[tid] = b1[tid];
    if (tid < 32) sb2[tid] = b2[tid];
    __syncthreads();
    float bb3 = b3[0];

    int lane = tid & 63;
    int gw = blockIdx.x * 4 + (tid >> 6);
    int nw = gridDim.x * 4;
    for (int p = gw; p < BB; p += nw) {
        int u = userIdx[p];
        int it = itemIdx[p] + N_USER;
        float ue = fin[u * 64 + lane];
        float ie = fin[it * 64 + lane];
        userE[p * 64 + lane] = ue;
        itemE[p * 64 + lane] = ie;
        float h = sb1[lane];
        #pragma unroll
        for (int k = 0; k < 64; ++k) h = fmaf(bcast(ue, k), sW1[k * 64 + lane], h);
        #pragma unroll
        for (int k = 0; k < 64; ++k) h = fmaf(bcast(ie, k), sW1[(k + 64) * 64 + lane], h);
        h = fmaxf(h, 0.f);
        float h2 = sb2[lane & 31];
        #pragma unroll
        for (int k = 0; k < 64; ++k) h2 = fmaf(bcast(h, k), sW2[k * 32 + (lane & 31)], h2);
        float c = (lane < 32) ? h2 * sW3[lane] : 0.f;
        #pragma unroll
        for (int o = 32; o >= 1; o >>= 1) c += __shfl_xor(c, o);
        if (lane == 0) pred[p] = c + bb3;
    }
}

// ---------------------------------------------------------------------------
extern "C" void kernel_launch(void* const* d_in, const int* in_sizes, int n_in,
                              void* d_out, int out_size, void* d_ws, size_t ws_size,
                              hipStream_t stream)
{
    const int*   userIdx = (const int*)d_in[0];
    const int*   itemIdx = (const int*)d_in[1];
    const float* uEmbd   = (const float*)d_in[2];
    const float* iEmbd   = (const float*)d_in[3];
    // slab order: 0 = lap(main), 1 = add, 2 = trust (matches softmax order)
    const int*   e_row[3] = {(const int*)d_in[4],  (const int*)d_in[10], (const int*)d_in[7]};
    const int*   e_col[3] = {(const int*)d_in[5],  (const int*)d_in[11], (const int*)d_in[8]};
    const float* e_val[3] = {(const float*)d_in[6], (const float*)d_in[12], (const float*)d_in[9]};
    const float* lin_W   = (const float*)d_in[13];
    const float* inter_W = (const float*)d_in[14];
    const float* attM_W  = (const float*)d_in[15];
    const float* attA_W  = (const float*)d_in[16];
    const float* attT_W  = (const float*)d_in[17];
    const float* lin_b   = (const float*)d_in[18];
    const float* inter_b = (const float*)d_in[19];
    const float* attM_b  = (const float*)d_in[20];
    const float* attA_b  = (const float*)d_in[21];
    const float* attT_b  = (const float*)d_in[22];
    const float* a_main  = (const float*)d_in[23];
    const float* a_add   = (const float*)d_in[24];
    const float* a_trust = (const float*)d_in[25];
    const float* W1 = (const float*)d_in[26];
    const float* b1 = (const float*)d_in[27];
    const float* W2 = (const float*)d_in[28];
    const float* b2 = (const float*)d_in[29];
    const float* W3 = (const float*)d_in[30];
    const float* b3 = (const float*)d_in[31];

    const float* attbq[3] = {attM_b, attA_b, attT_b};
    const float* avecq[3] = {a_main, a_add, a_trust};

    // workspace: GA [GB if it fits] | H0 H1 H2 | ECV | XB | RPS RPE CURS ATT
    size_t gwords = (size_t)NN * 128;       // ushorts per G buffer
    size_t need_big = 2 * gwords * 2 + (size_t)3 * ND * 2 + (size_t)3 * BUCKTOT * 8
                    + (size_t)ND * 2 + (size_t)6 * NN * 4 + (size_t)3 * NBUCK * 4 + 64;
    bool big = ws_size >= need_big;

    ushort* GA = (ushort*)d_ws;
    ushort* GB = big ? (GA + gwords) : GA;  // ping-pong only when space allows
    ushort* H0 = GB + gwords;
    ushort* H1 = H0 + ND;
    ushort* H2 = H1 + ND;
    int2*   ECV = (int2*)(H2 + ND);
    ushort* XB = (ushort*)(ECV + 3 * (size_t)BUCKTOT);
    int*    RPS = (int*)(XB + ND);
    int*    RPE = RPS + 3 * NN;
    int*    CURS = RPE + 3 * NN;
    float*  ATT = (float*)(CURS + 3 * NBUCK);

    ushort* Hs[3] = {H0, H1, H2};

    // d_out layout: pred[B] | userE[B*64] | itemE[B*64] | final[NN*64]
    float* outPred  = (float*)d_out;
    float* outUser  = outPred + BB;
    float* outItem  = outUser + BB * 64;
    float* outFinal = outItem + BB * 64;

    // WF (48 KB frag-order att weights) in outUser region (4 MB), which is
    // only overwritten by mlp_kernel at the very end (proven in round 2).
    ushort* WF = (ushort*)outUser;

    prep_kernel<<<7, 256, 0, stream>>>(attM_W, attA_W, attT_W, WF, CURS, ATT);
    ib_kernel<<<3 * BINB + 3125, 512, 0, stream>>>(
        e_row[0], e_col[0], e_val[0],
        e_row[1], e_col[1], e_val[1],
        e_row[2], e_col[2], e_val[2], CURS, ECV,
        (const float4*)uEmbd, (const float4*)iEmbd, XB, (float4*)outFinal);
    bsort_kernel<<<3 * NBUCK, 512, 0, stream>>>(CURS, ECV, RPS, RPE);

    for (int l = 0; l < 2; ++l) {
        const float* lw = lin_W + l * 4096;
        const float* iw = inter_W + l * 4096;
        const float* lb = lin_b + l * 64;
        const float* ib = inter_b + l * 64;

        if (big) {
            // spmm0 -> [dense0 | spmm1] -> [dense1 | spmm2] -> dense2
            spmm_kernel<<<3125, 256, 0, stream>>>(
                RPS, RPE, ECV, XB, GA);
            sd_kernel<<<DBLK + 3125, 256, 0, stream>>>(
                GA, Hs[0], lw, iw, lb, ib,
                WF + ((size_t)l * 3 + 0) * 4096, attbq[0] + l * 64, avecq[0] + l * 64,
                ATT + l * 3 + 0,
                RPS + NN, RPE + NN, ECV + (size_t)BUCKTOT, XB, GB);
            sd_kernel<<<DBLK + 3125, 256, 0, stream>>>(
                GB, Hs[1], lw, iw, lb, ib,
                WF + ((size_t)l * 3 + 1) * 4096, attbq[1] + l * 64, avecq[1] + l * 64,
                ATT + l * 3 + 1,
                RPS + 2 * NN, RPE + 2 * NN, ECV + 2 * (size_t)BUCKTOT, XB, GA);
            dense_kernel<<<DGRID, 256, 0, stream>>>(
                GA, Hs[2], lw, iw, lb, ib,
                WF + ((size_t)l * 3 + 2) * 4096, attbq[2] + l * 64, avecq[2] + l * 64,
                ATT + l * 3 + 2);
        } else {
            for (int q = 0; q < 3; ++q) {
                spmm_kernel<<<3125, 256, 0, stream>>>(
                    RPS + q * NN, RPE + q * NN, ECV + (size_t)q * BUCKTOT, XB, GA);
                dense_kernel<<<DGRID, 256, 0, stream>>>(
                    GA, Hs[q], lw, iw, lb, ib,
                    WF + ((size_t)l * 3 + q) * 4096, attbq[q] + l * 64, avecq[q] + l * 64,
                    ATT + l * 3 + q);
            }
        }
        combine_kernel<<<6250, 256, 0, stream>>>(
            (const unsigned long long*)Hs[0], (const unsigned long long*)Hs[1],
            (const unsigned long long*)Hs[2],
            ATT + l * 3, (ushort4*)XB, (float4*)outFinal,
            (l == 1) ? (1.f / 3.f) : 1.f, (l == 0) ? 1 : 0);
    }

    mlp_kernel<<<512, 256, 0, stream>>>(userIdx, itemIdx, outFinal,
                                        W1, b1, W2, b2, W3, b3,
                                        outPred, outUser, outItem);
}

// Round 7
// 819.593 us; speedup vs baseline: 1.1438x; 1.1438x over previous
//
#include <hip/hip_runtime.h>

// Problem constants
#define N_USER  60000
#define N_ITEM  40000
#define NN      100000          // total nodes
#define NNZ_E   1600000         // edges per relation
#define BB      16384           // batch pairs
#define ND      6400000         // NN * 64
#define ND4     1600000         // NN * 16 (float4 elements)
#define NCHUNK  6250            // NN / 16 row-chunks for dense
#define NBUCK   196             // row buckets of 512 rows
#define BUCK_CAP 9216           // fixed bucket capacity (mean 8163, sigma ~90)
#define BUCKTOT (NBUCK * BUCK_CAP)
#define BINB    196             // bin blocks per relation
#define EPB     8192            // edges per bin block (LDS-staged)

typedef __attribute__((ext_vector_type(8))) short bf16x8;
typedef __attribute__((ext_vector_type(8))) unsigned short u16x8;
typedef __attribute__((ext_vector_type(4))) float f32x4;

__device__ __forceinline__ float tanh_fast(float x) {
    x = fminf(fmaxf(x, -15.f), 15.f);
    float e = __expf(2.f * x);
    return (e - 1.f) / (e + 1.f);
}

__device__ __forceinline__ float bcast(float x, int k) {
    return __int_as_float(__builtin_amdgcn_readlane(__float_as_int(x), k));
}

__device__ __forceinline__ unsigned short f2bf(float f) {
    unsigned u = __float_as_uint(f);
    u += 0x7FFFu + ((u >> 16) & 1u);       // RNE
    return (unsigned short)(u >> 16);
}
__device__ __forceinline__ float bf2f(unsigned short s) {
    return __uint_as_float(((unsigned)s) << 16);
}

// frag-order LDS index for B-operand element (k, n) of a 64x64 matrix
__device__ __forceinline__ int widx(int k, int n) {
    return ((((n >> 4) * 2 + (k >> 5)) * 4 + ((k >> 3) & 3)) * 16 + (n & 15)) * 8 + (k & 7);
}

// ---------------------------------------------------------------------------
// fs = concat(uEmbd,iEmbd) fp32; XB = bf16(concat); cursors = b*CAP; att = 0
__global__ __launch_bounds__(256) void init_kernel(
    const float4* __restrict__ u, const float4* __restrict__ it,
    ushort* __restrict__ XB, float4* __restrict__ fs,
    int* __restrict__ CURS, float* __restrict__ attsum)
{
    int i = blockIdx.x * 256 + threadIdx.x;
    if (i < ND4) {
        float4 v = (i < N_USER * 16) ? u[i] : it[i - N_USER * 16];
        fs[i] = v;
        ushort4 b;
        b.x = f2bf(v.x); b.y = f2bf(v.y); b.z = f2bf(v.z); b.w = f2bf(v.w);
        ((ushort4*)XB)[i] = b;
    }
    if (i < 3 * NBUCK) CURS[i] = (i % NBUCK) * BUCK_CAP;
    if (i < 6) attsum[i] = 0.f;
}

// ---------------------------------------------------------------------------
// bin v4 (round-0 proven, verbatim): 512 threads, rows register-held,
// LDS bucket sort, nontemporal coalesced flush into reserved bucket runs.
__global__ __launch_bounds__(512) void bin_kernel(
    const int* __restrict__ rows0, const int* __restrict__ cols0, const float* __restrict__ vals0,
    const int* __restrict__ rows1, const int* __restrict__ cols1, const float* __restrict__ vals1,
    const int* __restrict__ rows2, const int* __restrict__ cols2, const float* __restrict__ vals2,
    int* __restrict__ CURS, int2* __restrict__ ECV)
{
    int rel = blockIdx.x / BINB;
    int blk = blockIdx.x % BINB;
    const int* rows; const int* cols; const float* vals;
    if (rel == 0) { rows = rows0; cols = cols0; vals = vals0; }
    else if (rel == 1) { rows = rows1; cols = cols1; vals = vals1; }
    else { rows = rows2; cols = cols2; vals = vals2; }
    long long* out = (long long*)(ECV + (size_t)rel * BUCKTOT);

    __shared__ int2 sStage[EPB];            // 64 KB
    __shared__ int hW[8 * NBUCK];           // per-wave hist
    __shared__ int lOff[NBUCK], lEnd[NBUCK], lCur[NBUCK], gB[NBUCK];
    __shared__ int wt[4];

    int t = threadIdx.x;
    int lane = t & 63, w = t >> 6;
    for (int i = t; i < 8 * NBUCK; i += 512) hW[i] = 0;
    __syncthreads();

    int base = blk * EPB;
    // pass 1: load rows once into regs + per-wave histogram
    int myrow[16];
    #pragma unroll
    for (int j = 0; j < 16; ++j) {
        int idx = base + j * 512 + t;
        myrow[j] = (idx < NNZ_E) ? __builtin_nontemporal_load(&rows[idx]) : -1;
        if (myrow[j] >= 0) atomicAdd(&hW[w * NBUCK + (myrow[j] >> 9)], 1);
    }
    __syncthreads();
    // combine + exclusive scan over 196 buckets (waves 0..3) + reservation
    if (t < 256) {
        int h = 0;
        if (t < NBUCK) {
            #pragma unroll
            for (int ww = 0; ww < 8; ++ww) h += hW[ww * NBUCK + t];
        }
        int sc = h;
        #pragma unroll
        for (int o = 1; o < 64; o <<= 1) {
            int u = __shfl_up(sc, o);
            if (lane >= o) sc += u;
        }
        if (lane == 63) wt[w] = sc;
        __syncthreads();
        int woff = 0;
        #pragma unroll
        for (int ww = 0; ww < 4; ++ww) if (ww < w) woff += wt[ww];
        int excl = woff + sc - h;
        if (t < NBUCK) {
            lOff[t] = excl;
            lEnd[t] = excl + h;
            lCur[t] = excl;
            gB[t] = h ? atomicAdd(&CURS[rel * NBUCK + t], h) : 0;
        }
    } else {
        __syncthreads();
    }
    __syncthreads();
    // pass 2: scatter into LDS stage sorted by bucket (cols/vals read here)
    #pragma unroll
    for (int j = 0; j < 16; ++j) {
        int idx = base + j * 512 + t;
        if (myrow[j] >= 0) {
            int c = __builtin_nontemporal_load(&cols[idx]);
            float v = __builtin_nontemporal_load(&vals[idx]);
            int b = myrow[j] >> 9;
            int pos = atomicAdd(&lCur[b], 1);
            int2 e;
            e.x = ((myrow[j] & 511) << 17) | c;
            e.y = __float_as_int(v);
            sStage[pos] = e;
        }
    }
    __syncthreads();
    // flush: wave w handles buckets w, w+8, ... ; contiguous nontemporal writes
    for (int b = w; b < NBUCK; b += 8) {
        int s = lOff[b], e = lEnd[b];
        int gb = gB[b];
        int lim = (b + 1) * BUCK_CAP;
        for (int i = s + lane; i < e; i += 64) {
            int d = gb + (i - s);
            if (d < lim) {
                int2 ev = sStage[i];
                long long packed = (((long long)(unsigned)ev.y) << 32) | (unsigned)ev.x;
                __builtin_nontemporal_store(packed, &out[d]);
            }
        }
    }
}

// ---------------------------------------------------------------------------
// bsort v3: proven v2 body + degree-equalization PERM emission.
// After the row-sort, each bucket's 512 rows are counting-sorted by degree
// (64 bins); PERM[rel*NN + bucket*512 + pos] = row. spmm waves then draw 8
// near-equal-degree rows, so cm ~= mean instead of max (Poisson(16) max-of-8
// wastes ~25-30% of gather iterations). G stays bit-identical.
__global__ __launch_bounds__(512) void bsort_kernel(
    const int* __restrict__ CURS, int2* __restrict__ ECV,
    int* __restrict__ RPS, int* __restrict__ RPE, int* __restrict__ PERM)
{
    int rel = blockIdx.x / NBUCK;
    int b   = blockIdx.x % NBUCK;
    int start = b * BUCK_CAP;
    int cnt = CURS[rel * NBUCK + b] - start;
    if (cnt > BUCK_CAP) cnt = BUCK_CAP;     // never in practice
    int2* ecv = ECV + (size_t)rel * BUCKTOT;

    __shared__ int2 sStage[BUCK_CAP];       // 72 KB
    __shared__ int sOff[512], sCnt[512];
    __shared__ int wt[8];
    __shared__ int dh[64];
    int t = threadIdx.x;
    int lane = t & 63, w = t >> 6;
    sCnt[t] = 0;
    __syncthreads();
    // load edges into regs + histogram
    int2 e[18];
    #pragma unroll
    for (int j = 0; j < 18; ++j) {
        int i = t + j * 512;
        if (i < cnt) {
            e[j] = ecv[start + i];
            atomicAdd(&sCnt[((unsigned)e[j].x) >> 17], 1);
        }
    }
    __syncthreads();
    // exclusive scan of 512 counts (8 waves)
    int h = sCnt[t];
    int myCnt = h;                           // this thread's row degree
    int sc = h;
    #pragma unroll
    for (int o = 1; o < 64; o <<= 1) {
        int u = __shfl_up(sc, o);
        if (lane >= o) sc += u;
    }
    if (lane == 63) wt[w] = sc;
    __syncthreads();
    int woff = 0;
    #pragma unroll
    for (int ww = 0; ww < 8; ++ww) if (ww < w) woff += wt[ww];
    int excl = woff + sc - h;
    __syncthreads();
    sOff[t] = excl;
    sCnt[t] = excl;                          // cursor
    __syncthreads();
    // reorder from regs into LDS stage
    #pragma unroll
    for (int j = 0; j < 18; ++j) {
        int i = t + j * 512;
        if (i < cnt) {
            int rl = ((unsigned)e[j].x) >> 17;
            int pos = atomicAdd(&sCnt[rl], 1);
            int2 o2; o2.x = e[j].x & 0x1FFFF; o2.y = e[j].y;
            sStage[pos] = o2;
        }
    }
    __syncthreads();
    // stream back in place (coalesced)
    for (int i = t; i < cnt; i += 512) ecv[start + i] = sStage[i];
    // RPS/RPE: one row per thread
    int row = b * 512 + t;
    if (row < NN) {
        RPS[rel * NN + row] = start + sOff[t];
        RPE[rel * NN + row] = start + sCnt[t];
    }

    // ---- degree-equalization permutation (counting sort, 64 bins) ----
    // valid rows: bins 0..62 (degree clamped); invalid rows (>= NN, only in
    // the last bucket): bin 63, sorted last, positions beyond NN are skipped.
    int dbin = (row < NN) ? min(myCnt, 62) : 63;
    if (t < 64) dh[t] = 0;
    __syncthreads();
    atomicAdd(&dh[dbin], 1);
    __syncthreads();
    if (t < 64) {
        int v = dh[t];
        int sc2 = v;
        #pragma unroll
        for (int o = 1; o < 64; o <<= 1) {
            int u2 = __shfl_up(sc2, o);
            if (t >= o) sc2 += u2;
        }
        dh[t] = sc2 - v;                     // exclusive bin offsets -> cursors
    }
    __syncthreads();
    int pos = atomicAdd(&dh[dbin], 1);
    int slot = b * 512 + pos;
    if (row < NN && slot < NN) PERM[rel * NN + slot] = row;
}

// ---------------------------------------------------------------------------
// SpMM v8: round-0 proven v5 body; rows drawn via degree-sorted PERM so the
// wave's 8 rows have near-equal edge counts (cm ~= mean, not max).
// 8 rows per wave, 8 lanes per row, ushort8 (8 dims, 16B) per lane.
// G layout: [r*128 .. +63] = A = s1+x, [+64 .. +127] = S2.
__global__ __launch_bounds__(256, 4) void spmm_kernel(
    const int* __restrict__ RPS, const int* __restrict__ RPE,
    const int2* __restrict__ ecv, const int* __restrict__ PERM,
    const ushort* __restrict__ XB, ushort* __restrict__ G)
{
    int t = threadIdx.x;
    int lane = t & 63;
    int wv = t >> 6;
    int dl = lane & 7;                  // dims 8*dl .. 8*dl+7
    int g = blockIdx.x * 32 + wv * 8 + (lane >> 3);   // 3125*32 = NN exactly
    int r = PERM[g];
    int ea = RPS[r], eb = RPE[r];
    int cnt = eb - ea;
    int cm = cnt;
    cm = max(cm, __shfl_xor(cm, 8));
    cm = max(cm, __shfl_xor(cm, 16));
    cm = max(cm, __shfl_xor(cm, 32));
    u16x8 xo8 = *(const u16x8*)&XB[(size_t)r * 64 + 8 * dl];
    float s1[8] = {0.f, 0.f, 0.f, 0.f, 0.f, 0.f, 0.f, 0.f};
    float s2[8] = {0.f, 0.f, 0.f, 0.f, 0.f, 0.f, 0.f, 0.f};
    for (int base = 0; base < cm; base += 4) {
        float vv[4]; u16x8 xx[4];
        #pragma unroll
        for (int j = 0; j < 4; ++j) {
            int i = base + j;
            bool ok = i < cnt;
            int is = ea + (ok ? i : 0);
            int2 cv = ecv[is];
            vv[j] = ok ? __int_as_float(cv.y) : 0.f;
            xx[j] = *(const u16x8*)&XB[(size_t)cv.x * 64 + 8 * dl];
        }
        #pragma unroll
        for (int j = 0; j < 4; ++j) {
            float v = vv[j];
            #pragma unroll
            for (int d = 0; d < 8; ++d) {
                float x = bf2f(xx[j][d]);
                s1[d] += v * x;
                s2[d] += v * x * x;
            }
        }
    }
    u16x8 o1, o2;
    #pragma unroll
    for (int d = 0; d < 8; ++d) {
        o1[d] = f2bf(s1[d] + bf2f(xo8[d]));
        o2[d] = f2bf(s2[d]);
    }
    *(u16x8*)&G[(size_t)r * 128 + 8 * dl]      = o1;
    *(u16x8*)&G[(size_t)r * 128 + 64 + 8 * dl] = o2;
}

// ---------------------------------------------------------------------------
// MFMA dense (round-0 proven, verbatim): H = A@L + S2@I + bias; H out bf16;
// att = sum tanh(H@attW + attb) * avec, one atomic per wave. Grid 512.
__global__ __launch_bounds__(256) void dense_kernel(
    const ushort* __restrict__ G, ushort* __restrict__ Hout,
    const float* __restrict__ linW, const float* __restrict__ interW,
    const float* __restrict__ linb, const float* __restrict__ interb,
    const float* __restrict__ attW, const float* __restrict__ attb,
    const float* __restrict__ avec, float* __restrict__ attsum)
{
    __shared__ short sL[4096], sI[4096], sW[4096];
    __shared__ float sH[4 * 16 * 65];
    __shared__ float sBias[64], sAttb[64], sAvec[64];

    int tid = threadIdx.x;
    for (int i = tid; i < 4096; i += 256) {
        int k = i >> 6, n = i & 63, ix = widx(k, n);
        sL[ix] = (short)f2bf(linW[i]);
        sI[ix] = (short)f2bf(interW[i]);
        sW[ix] = (short)f2bf(attW[i]);
    }
    if (tid < 64) {
        sBias[tid] = linb[tid] + interb[tid];
        sAttb[tid] = attb[tid];
        sAvec[tid] = avec[tid];
    }
    __syncthreads();

    const bf16x8* pL = (const bf16x8*)sL;
    const bf16x8* pI = (const bf16x8*)sI;
    const bf16x8* pW = (const bf16x8*)sW;

    int lane = tid & 63;
    int wv = tid >> 6;
    int nl = lane & 15;
    int q  = lane >> 4;
    float* myH = sH + wv * (16 * 65);
    int gw = blockIdx.x * 4 + wv;
    int nw = gridDim.x * 4;
    float att_acc = 0.f;

    for (int c = gw; c < NCHUNK; c += nw) {
        int r0 = c * 16;
        const bf16x8* gp = (const bf16x8*)(G + (size_t)(r0 + nl) * 128);
        bf16x8 Ah[2], Qh[2];
        Ah[0] = gp[q];         Ah[1] = gp[4 + q];
        Qh[0] = gp[8 + q];     Qh[1] = gp[12 + q];
        #pragma unroll
        for (int nt = 0; nt < 4; ++nt) {
            float b = sBias[nt * 16 + nl];
            f32x4 acc = {b, b, b, b};
            #pragma unroll
            for (int kh = 0; kh < 2; ++kh) {
                int f = ((nt * 2 + kh) * 4 + q) * 16 + nl;
                acc = __builtin_amdgcn_mfma_f32_16x16x32_bf16(Ah[kh], pL[f], acc, 0, 0, 0);
                acc = __builtin_amdgcn_mfma_f32_16x16x32_bf16(Qh[kh], pI[f], acc, 0, 0, 0);
            }
            #pragma unroll
            for (int reg = 0; reg < 4; ++reg) {
                int row = q * 4 + reg;
                Hout[(size_t)(r0 + row) * 64 + nt * 16 + nl] = f2bf(acc[reg]);
                myH[row * 65 + nt * 16 + nl] = acc[reg];
            }
        }
        // attention
        bf16x8 Th[2];
        #pragma unroll
        for (int kh = 0; kh < 2; ++kh) {
            #pragma unroll
            for (int j = 0; j < 8; ++j)
                Th[kh][j] = (short)f2bf(myH[nl * 65 + kh * 32 + q * 8 + j]);
        }
        #pragma unroll
        for (int nt = 0; nt < 4; ++nt) {
            float b = sAttb[nt * 16 + nl];
            f32x4 acc = {b, b, b, b};
            #pragma unroll
            for (int kh = 0; kh < 2; ++kh) {
                int f = ((nt * 2 + kh) * 4 + q) * 16 + nl;
                acc = __builtin_amdgcn_mfma_f32_16x16x32_bf16(Th[kh], pW[f], acc, 0, 0, 0);
            }
            float av = sAvec[nt * 16 + nl];
            #pragma unroll
            for (int reg = 0; reg < 4; ++reg)
                att_acc += tanh_fast(acc[reg]) * av;
        }
    }
    #pragma unroll
    for (int o = 32; o >= 1; o >>= 1) att_acc += __shfl_xor(att_acc, o);
    if (lane == 0) atomicAdd(attsum, att_acc);
}

// ---------------------------------------------------------------------------
// beta = softmax(attsum/NN); x = b0*hM + b1*hA + b2*hT (bf16 in, read-once
// nontemporal via u64); XB = bf16(x) (skipped last layer); fs = (fs+x)*scale
__global__ __launch_bounds__(256) void combine_kernel(
    const unsigned long long* __restrict__ hM,
    const unsigned long long* __restrict__ hA,
    const unsigned long long* __restrict__ hT,
    const float* __restrict__ attsum,
    ushort4* __restrict__ XB, float4* __restrict__ fs, float scale, int doXB)
{
    float w0 = attsum[0] * (1.f / NN);
    float w1 = attsum[1] * (1.f / NN);
    float w2 = attsum[2] * (1.f / NN);
    float m = fmaxf(w0, fmaxf(w1, w2));
    float e0 = __expf(w0 - m), e1 = __expf(w1 - m), e2 = __expf(w2 - m);
    float inv = 1.f / (e0 + e1 + e2);
    float b0 = e0 * inv, b1 = e1 * inv, b2 = e2 * inv;

    int i = blockIdx.x * 256 + threadIdx.x;
    if (i >= ND4) return;
    unsigned long long pm = __builtin_nontemporal_load(&hM[i]);
    unsigned long long pa = __builtin_nontemporal_load(&hA[i]);
    unsigned long long pt = __builtin_nontemporal_load(&hT[i]);
    float4 x;
    x.x = b0 * bf2f((unsigned short)pm)         + b1 * bf2f((unsigned short)pa)         + b2 * bf2f((unsigned short)pt);
    x.y = b0 * bf2f((unsigned short)(pm >> 16)) + b1 * bf2f((unsigned short)(pa >> 16)) + b2 * bf2f((unsigned short)(pt >> 16));
    x.z = b0 * bf2f((unsigned short)(pm >> 32)) + b1 * bf2f((unsigned short)(pa >> 32)) + b2 * bf2f((unsigned short)(pt >> 32));
    x.w = b0 * bf2f((unsigned short)(pm >> 48)) + b1 * bf2f((unsigned short)(pa >> 48)) + b2 * bf2f((unsigned short)(pt >> 48));
    if (doXB) {
        ushort4 bo;
        bo.x = f2bf(x.x); bo.y = f2bf(x.y); bo.z = f2bf(x.z); bo.w = f2bf(x.w);
        XB[i] = bo;
    }
    float4 f = fs[i];
    f.x = (f.x + x.x) * scale;
    f.y = (f.y + x.y) * scale;
    f.z = (f.z + x.z) * scale;
    f.w = (f.w + x.w) * scale;
    fs[i] = f;
}

// ---------------------------------------------------------------------------
__global__ __launch_bounds__(256) void mlp_kernel(
    const int* __restrict__ userIdx, const int* __restrict__ itemIdx,
    const float* __restrict__ fin,
    const float* __restrict__ W1, const float* __restrict__ b1,
    const float* __restrict__ W2, const float* __restrict__ b2,
    const float* __restrict__ W3, const float* __restrict__ b3,
    float* __restrict__ pred, float* __restrict__ userE, float* __restrict__ itemE)
{
    __shared__ float sW1[128 * 64];
    __shared__ float sW2[64 * 32];
    __shared__ float sW3[32];
    __shared__ float sb1[64];
    __shared__ float sb2[32];
    int tid = threadIdx.x;
    for (int i = tid; i < 8192; i += 256) sW1[i] = W1[i];
    for (int i = tid; i < 2048; i += 256) sW2[i] = W2[i];
    if (tid < 32) sW3[tid] = W3[tid];
    if (tid < 64) sb1[tid] = b1[tid];
    if (tid < 32) sb2[tid] = b2[tid];
    __syncthreads();
    float bb3 = b3[0];

    int lane = tid & 63;
    int gw = blockIdx.x * 4 + (tid >> 6);
    int nw = gridDim.x * 4;
    for (int p = gw; p < BB; p += nw) {
        int u = userIdx[p];
        int it = itemIdx[p] + N_USER;
        float ue = fin[u * 64 + lane];
        float ie = fin[it * 64 + lane];
        userE[p * 64 + lane] = ue;
        itemE[p * 64 + lane] = ie;
        float h = sb1[lane];
        #pragma unroll
        for (int k = 0; k < 64; ++k) h = fmaf(bcast(ue, k), sW1[k * 64 + lane], h);
        #pragma unroll
        for (int k = 0; k < 64; ++k) h = fmaf(bcast(ie, k), sW1[(k + 64) * 64 + lane], h);
        h = fmaxf(h, 0.f);
        float h2 = sb2[lane & 31];
        #pragma unroll
        for (int k = 0; k < 64; ++k) h2 = fmaf(bcast(h, k), sW2[k * 32 + (lane & 31)], h2);
        float c = (lane < 32) ? h2 * sW3[lane] : 0.f;
        #pragma unroll
        for (int o = 32; o >= 1; o >>= 1) c += __shfl_xor(c, o);
        if (lane == 0) pred[p] = c + bb3;
    }
}

// ---------------------------------------------------------------------------
extern "C" void kernel_launch(void* const* d_in, const int* in_sizes, int n_in,
                              void* d_out, int out_size, void* d_ws, size_t ws_size,
                              hipStream_t stream)
{
    const int*   userIdx = (const int*)d_in[0];
    const int*   itemIdx = (const int*)d_in[1];
    const float* uEmbd   = (const float*)d_in[2];
    const float* iEmbd   = (const float*)d_in[3];
    // slab order: 0 = lap(main), 1 = add, 2 = trust (matches softmax order)
    const int*   e_row[3] = {(const int*)d_in[4],  (const int*)d_in[10], (const int*)d_in[7]};
    const int*   e_col[3] = {(const int*)d_in[5],  (const int*)d_in[11], (const int*)d_in[8]};
    const float* e_val[3] = {(const float*)d_in[6], (const float*)d_in[12], (const float*)d_in[9]};
    const float* lin_W   = (const float*)d_in[13];
    const float* inter_W = (const float*)d_in[14];
    const float* attM_W  = (const float*)d_in[15];
    const float* attA_W  = (const float*)d_in[16];
    const float* attT_W  = (const float*)d_in[17];
    const float* lin_b   = (const float*)d_in[18];
    const float* inter_b = (const float*)d_in[19];
    const float* attM_b  = (const float*)d_in[20];
    const float* attA_b  = (const float*)d_in[21];
    const float* attT_b  = (const float*)d_in[22];
    const float* a_main  = (const float*)d_in[23];
    const float* a_add   = (const float*)d_in[24];
    const float* a_trust = (const float*)d_in[25];
    const float* W1 = (const float*)d_in[26];
    const float* b1 = (const float*)d_in[27];
    const float* W2 = (const float*)d_in[28];
    const float* b2 = (const float*)d_in[29];
    const float* W3 = (const float*)d_in[30];
    const float* b3 = (const float*)d_in[31];

    const float* attWq[3] = {attM_W, attA_W, attT_W};
    const float* attbq[3] = {attM_b, attA_b, attT_b};
    const float* avecq[3] = {a_main, a_add, a_trust};

    // workspace layout (~124 MB = round-0 + PERM):
    // G (bf16 A|S2 interleaved) | H0,H1,H2 | ECV | XB | RPS,RPE | CURS | ATT | PERM
    ushort* G  = (ushort*)d_ws;
    ushort* H0 = G + (size_t)NN * 128;
    ushort* H1 = H0 + ND;
    ushort* H2 = H1 + ND;
    int2*   ECV = (int2*)(H2 + ND);
    ushort* XB = (ushort*)(ECV + 3 * (size_t)BUCKTOT);
    int*    RPS = (int*)(XB + ND);
    int*    RPE = RPS + 3 * NN;
    int*    CURS = RPE + 3 * NN;
    float*  ATT = (float*)(CURS + 3 * NBUCK);
    int*    PERM = (int*)(ATT + 16);

    ushort* Hs[3] = {H0, H1, H2};

    // d_out layout: pred[B] | userE[B*64] | itemE[B*64] | final[NN*64]
    float* outPred  = (float*)d_out;
    float* outUser  = outPred + BB;
    float* outItem  = outUser + BB * 64;
    float* outFinal = outItem + BB * 64;

    init_kernel<<<6250, 256, 0, stream>>>((const float4*)uEmbd, (const float4*)iEmbd,
                                          XB, (float4*)outFinal, CURS, ATT);
    bin_kernel<<<3 * BINB, 512, 0, stream>>>(
        e_row[0], e_col[0], e_val[0],
        e_row[1], e_col[1], e_val[1],
        e_row[2], e_col[2], e_val[2], CURS, ECV);
    bsort_kernel<<<3 * NBUCK, 512, 0, stream>>>(CURS, ECV, RPS, RPE, PERM);

    for (int l = 0; l < 2; ++l) {
        const float* lw = lin_W + l * 4096;
        const float* iw = inter_W + l * 4096;
        const float* lb = lin_b + l * 64;
        const float* ib = inter_b + l * 64;

        for (int q = 0; q < 3; ++q) {
            spmm_kernel<<<3125, 256, 0, stream>>>(
                RPS + q * NN, RPE + q * NN, ECV + (size_t)q * BUCKTOT,
                PERM + q * NN, XB, G);
            dense_kernel<<<512, 256, 0, stream>>>(
                G, Hs[q], lw, iw, lb, ib,
                attWq[q] + l * 4096, attbq[q] + l * 64, avecq[q] + l * 64,
                ATT + l * 3 + q);
        }
        combine_kernel<<<6250, 256, 0, stream>>>(
            (const unsigned long long*)Hs[0], (const unsigned long long*)Hs[1],
            (const unsigned long long*)Hs[2],
            ATT + l * 3, (ushort4*)XB, (float4*)outFinal,
            (l == 1) ? (1.f / 3.f) : 1.f, (l == 0) ? 1 : 0);
    }

    mlp_kernel<<<512, 256, 0, stream>>>(userIdx, itemIdx, outFinal,
                                        W1, b1, W2, b2, W3, b3,
                                        outPred, outUser, outItem);
}

// Round 8
// 786.525 us; speedup vs baseline: 1.1918x; 1.0420x over previous
//
#include <hip/hip_runtime.h>

// Problem constants
#define N_USER  60000
#define N_ITEM  40000
#define NN      100000          // total nodes
#define NNZ_E   1600000         // edges per relation
#define BB      16384           // batch pairs
#define ND      6400000         // NN * 64
#define ND4     1600000         // NN * 16 (float4 elements)
#define NCHUNK  6250            // NN / 16 row-chunks for dense
#define NBUCK   196             // row buckets of 512 rows
#define BUCK_CAP 9216           // fixed bucket capacity (mean 8163, sigma ~90)
#define BUCKTOT (NBUCK * BUCK_CAP)
#define BINB    196             // bin blocks per relation
#define EPB     8192            // edges per bin block (LDS-staged)

typedef __attribute__((ext_vector_type(8))) short bf16x8;
typedef __attribute__((ext_vector_type(8))) unsigned short u16x8;
typedef __attribute__((ext_vector_type(4))) float f32x4;

__device__ __forceinline__ float tanh_fast(float x) {
    x = fminf(fmaxf(x, -15.f), 15.f);
    float e = __expf(2.f * x);
    return (e - 1.f) / (e + 1.f);
}

__device__ __forceinline__ float bcast(float x, int k) {
    return __int_as_float(__builtin_amdgcn_readlane(__float_as_int(x), k));
}

__device__ __forceinline__ unsigned short f2bf(float f) {
    unsigned u = __float_as_uint(f);
    u += 0x7FFFu + ((u >> 16) & 1u);       // RNE
    return (unsigned short)(u >> 16);
}
__device__ __forceinline__ float bf2f(unsigned short s) {
    return __uint_as_float(((unsigned)s) << 16);
}

// frag-order LDS index for B-operand element (k, n) of a 64x64 matrix
__device__ __forceinline__ int widx(int k, int n) {
    return ((((n >> 4) * 2 + (k >> 5)) * 4 + ((k >> 3) & 3)) * 16 + (n & 15)) * 8 + (k & 7);
}

// ---------------------------------------------------------------------------
// fs = concat(uEmbd,iEmbd) fp32; XB = bf16(concat); cursors = b*CAP; att = 0
__global__ __launch_bounds__(256) void init_kernel(
    const float4* __restrict__ u, const float4* __restrict__ it,
    ushort* __restrict__ XB, float4* __restrict__ fs,
    int* __restrict__ CURS, float* __restrict__ attsum)
{
    int i = blockIdx.x * 256 + threadIdx.x;
    if (i < ND4) {
        float4 v = (i < N_USER * 16) ? u[i] : it[i - N_USER * 16];
        fs[i] = v;
        ushort4 b;
        b.x = f2bf(v.x); b.y = f2bf(v.y); b.z = f2bf(v.z); b.w = f2bf(v.w);
        ((ushort4*)XB)[i] = b;
    }
    if (i < 3 * NBUCK) CURS[i] = (i % NBUCK) * BUCK_CAP;
    if (i < 6) attsum[i] = 0.f;
}

// ---------------------------------------------------------------------------
// bin v4 (round-0 proven, verbatim): 512 threads, rows register-held,
// LDS bucket sort, nontemporal coalesced flush into reserved bucket runs.
__global__ __launch_bounds__(512) void bin_kernel(
    const int* __restrict__ rows0, const int* __restrict__ cols0, const float* __restrict__ vals0,
    const int* __restrict__ rows1, const int* __restrict__ cols1, const float* __restrict__ vals1,
    const int* __restrict__ rows2, const int* __restrict__ cols2, const float* __restrict__ vals2,
    int* __restrict__ CURS, int2* __restrict__ ECV)
{
    int rel = blockIdx.x / BINB;
    int blk = blockIdx.x % BINB;
    const int* rows; const int* cols; const float* vals;
    if (rel == 0) { rows = rows0; cols = cols0; vals = vals0; }
    else if (rel == 1) { rows = rows1; cols = cols1; vals = vals1; }
    else { rows = rows2; cols = cols2; vals = vals2; }
    long long* out = (long long*)(ECV + (size_t)rel * BUCKTOT);

    __shared__ int2 sStage[EPB];            // 64 KB
    __shared__ int hW[8 * NBUCK];           // per-wave hist
    __shared__ int lOff[NBUCK], lEnd[NBUCK], lCur[NBUCK], gB[NBUCK];
    __shared__ int wt[4];

    int t = threadIdx.x;
    int lane = t & 63, w = t >> 6;
    for (int i = t; i < 8 * NBUCK; i += 512) hW[i] = 0;
    __syncthreads();

    int base = blk * EPB;
    // pass 1: load rows once into regs + per-wave histogram
    int myrow[16];
    #pragma unroll
    for (int j = 0; j < 16; ++j) {
        int idx = base + j * 512 + t;
        myrow[j] = (idx < NNZ_E) ? __builtin_nontemporal_load(&rows[idx]) : -1;
        if (myrow[j] >= 0) atomicAdd(&hW[w * NBUCK + (myrow[j] >> 9)], 1);
    }
    __syncthreads();
    // combine + exclusive scan over 196 buckets (waves 0..3) + reservation
    if (t < 256) {
        int h = 0;
        if (t < NBUCK) {
            #pragma unroll
            for (int ww = 0; ww < 8; ++ww) h += hW[ww * NBUCK + t];
        }
        int sc = h;
        #pragma unroll
        for (int o = 1; o < 64; o <<= 1) {
            int u = __shfl_up(sc, o);
            if (lane >= o) sc += u;
        }
        if (lane == 63) wt[w] = sc;
        __syncthreads();
        int woff = 0;
        #pragma unroll
        for (int ww = 0; ww < 4; ++ww) if (ww < w) woff += wt[ww];
        int excl = woff + sc - h;
        if (t < NBUCK) {
            lOff[t] = excl;
            lEnd[t] = excl + h;
            lCur[t] = excl;
            gB[t] = h ? atomicAdd(&CURS[rel * NBUCK + t], h) : 0;
        }
    } else {
        __syncthreads();
    }
    __syncthreads();
    // pass 2: scatter into LDS stage sorted by bucket (cols/vals read here)
    #pragma unroll
    for (int j = 0; j < 16; ++j) {
        int idx = base + j * 512 + t;
        if (myrow[j] >= 0) {
            int c = __builtin_nontemporal_load(&cols[idx]);
            float v = __builtin_nontemporal_load(&vals[idx]);
            int b = myrow[j] >> 9;
            int pos = atomicAdd(&lCur[b], 1);
            int2 e;
            e.x = ((myrow[j] & 511) << 17) | c;
            e.y = __float_as_int(v);
            sStage[pos] = e;
        }
    }
    __syncthreads();
    // flush: wave w handles buckets w, w+8, ... ; contiguous nontemporal writes
    for (int b = w; b < NBUCK; b += 8) {
        int s = lOff[b], e = lEnd[b];
        int gb = gB[b];
        int lim = (b + 1) * BUCK_CAP;
        for (int i = s + lane; i < e; i += 64) {
            int d = gb + (i - s);
            if (d < lim) {
                int2 ev = sStage[i];
                long long packed = (((long long)(unsigned)ev.y) << 32) | (unsigned)ev.x;
                __builtin_nontemporal_store(packed, &out[d]);
            }
        }
    }
}

// ---------------------------------------------------------------------------
// bsort v2 (round-0 proven, verbatim): 512 threads, edges register-held,
// row-sort in LDS, stream back in place, emit RPS/RPE.
__global__ __launch_bounds__(512) void bsort_kernel(
    const int* __restrict__ CURS, int2* __restrict__ ECV,
    int* __restrict__ RPS, int* __restrict__ RPE)
{
    int rel = blockIdx.x / NBUCK;
    int b   = blockIdx.x % NBUCK;
    int start = b * BUCK_CAP;
    int cnt = CURS[rel * NBUCK + b] - start;
    if (cnt > BUCK_CAP) cnt = BUCK_CAP;     // never in practice
    int2* ecv = ECV + (size_t)rel * BUCKTOT;

    __shared__ int2 sStage[BUCK_CAP];       // 72 KB
    __shared__ int sOff[512], sCnt[512];
    __shared__ int wt[8];
    int t = threadIdx.x;
    int lane = t & 63, w = t >> 6;
    sCnt[t] = 0;
    __syncthreads();
    // load edges into regs + histogram
    int2 e[18];
    #pragma unroll
    for (int j = 0; j < 18; ++j) {
        int i = t + j * 512;
        if (i < cnt) {
            e[j] = ecv[start + i];
            atomicAdd(&sCnt[((unsigned)e[j].x) >> 17], 1);
        }
    }
    __syncthreads();
    // exclusive scan of 512 counts (8 waves)
    int h = sCnt[t];
    int sc = h;
    #pragma unroll
    for (int o = 1; o < 64; o <<= 1) {
        int u = __shfl_up(sc, o);
        if (lane >= o) sc += u;
    }
    if (lane == 63) wt[w] = sc;
    __syncthreads();
    int woff = 0;
    #pragma unroll
    for (int ww = 0; ww < 8; ++ww) if (ww < w) woff += wt[ww];
    int excl = woff + sc - h;
    __syncthreads();
    sOff[t] = excl;
    sCnt[t] = excl;                          // cursor
    __syncthreads();
    // reorder from regs into LDS stage
    #pragma unroll
    for (int j = 0; j < 18; ++j) {
        int i = t + j * 512;
        if (i < cnt) {
            int rl = ((unsigned)e[j].x) >> 17;
            int pos = atomicAdd(&sCnt[rl], 1);
            int2 o2; o2.x = e[j].x & 0x1FFFF; o2.y = e[j].y;
            sStage[pos] = o2;
        }
    }
    __syncthreads();
    // stream back in place (coalesced)
    for (int i = t; i < cnt; i += 512) ecv[start + i] = sStage[i];
    // RPS/RPE: one row per thread
    int row = b * 512 + t;
    if (row < NN) {
        RPS[rel * NN + row] = start + sOff[t];
        RPE[rel * NN + row] = start + sCnt[t];
    }
}

// ---------------------------------------------------------------------------
// SpMM body (round-0 proven v5, verbatim): 8 rows per wave, 8 lanes per row,
// ushort8 (8 dims, 16B) per lane; batch-4 keeps 32 edges in flight per wave.
// G layout: [r*128 .. +63] = A = s1+x, [+64 .. +127] = S2.
__device__ __forceinline__ void spmm_body(
    int t, int bid,
    const int* __restrict__ RPS, const int* __restrict__ RPE,
    const int2* __restrict__ ecv, const ushort* __restrict__ XB,
    ushort* __restrict__ G)
{
    int lane = t & 63;
    int wv = t >> 6;
    int dl = lane & 7;                  // dims 8*dl .. 8*dl+7
    int r = bid * 32 + wv * 8 + (lane >> 3);   // 3125*32 = NN exactly
    int ea = RPS[r], eb = RPE[r];
    int cnt = eb - ea;
    int cm = cnt;
    cm = max(cm, __shfl_xor(cm, 8));
    cm = max(cm, __shfl_xor(cm, 16));
    cm = max(cm, __shfl_xor(cm, 32));
    u16x8 xo8 = *(const u16x8*)&XB[(size_t)r * 64 + 8 * dl];
    float s1[8] = {0.f, 0.f, 0.f, 0.f, 0.f, 0.f, 0.f, 0.f};
    float s2[8] = {0.f, 0.f, 0.f, 0.f, 0.f, 0.f, 0.f, 0.f};
    for (int base = 0; base < cm; base += 4) {
        float vv[4]; u16x8 xx[4];
        #pragma unroll
        for (int j = 0; j < 4; ++j) {
            int i = base + j;
            bool ok = i < cnt;
            int is = ea + (ok ? i : 0);
            int2 cv = ecv[is];
            vv[j] = ok ? __int_as_float(cv.y) : 0.f;
            xx[j] = *(const u16x8*)&XB[(size_t)cv.x * 64 + 8 * dl];
        }
        #pragma unroll
        for (int j = 0; j < 4; ++j) {
            float v = vv[j];
            #pragma unroll
            for (int d = 0; d < 8; ++d) {
                float x = bf2f(xx[j][d]);
                s1[d] += v * x;
                s2[d] += v * x * x;
            }
        }
    }
    u16x8 o1, o2;
    #pragma unroll
    for (int d = 0; d < 8; ++d) {
        o1[d] = f2bf(s1[d] + bf2f(xo8[d]));
        o2[d] = f2bf(s2[d]);
    }
    *(u16x8*)&G[(size_t)r * 128 + 8 * dl]      = o1;
    *(u16x8*)&G[(size_t)r * 128 + 64 + 8 * dl] = o2;
}

// cold variant: (256,4) — round-0 proven throttle for the first, L3-cold
// dispatch (round 3 showed (256,8) on the cold dispatch spirals to 144us).
__global__ __launch_bounds__(256, 4) void spmm_kernel(
    const int* __restrict__ RPS, const int* __restrict__ RPE,
    const int2* __restrict__ ecv,
    const ushort* __restrict__ XB, ushort* __restrict__ G)
{
    spmm_body(threadIdx.x, blockIdx.x, RPS, RPE, ecv, XB, G);
}

// warm variant: (256,8) — 8 blocks/CU, 32 waves/CU. Round-3 evidence: warm
// dispatches under (256,8) stayed <=56us; doubling resident gather waves on
// the latency-bound gather should cut them toward ~45us.
__global__ __launch_bounds__(256, 8) void spmm8_kernel(
    const int* __restrict__ RPS, const int* __restrict__ RPE,
    const int2* __restrict__ ecv,
    const ushort* __restrict__ XB, ushort* __restrict__ G)
{
    spmm_body(threadIdx.x, blockIdx.x, RPS, RPE, ecv, XB, G);
}

// ---------------------------------------------------------------------------
// MFMA dense (round-0 proven, verbatim): H = A@L + S2@I + bias; H out bf16;
// att = sum tanh(H@attW + attb) * avec, one atomic per wave. Grid 512.
__global__ __launch_bounds__(256) void dense_kernel(
    const ushort* __restrict__ G, ushort* __restrict__ Hout,
    const float* __restrict__ linW, const float* __restrict__ interW,
    const float* __restrict__ linb, const float* __restrict__ interb,
    const float* __restrict__ attW, const float* __restrict__ attb,
    const float* __restrict__ avec, float* __restrict__ attsum)
{
    __shared__ short sL[4096], sI[4096], sW[4096];
    __shared__ float sH[4 * 16 * 65];
    __shared__ float sBias[64], sAttb[64], sAvec[64];

    int tid = threadIdx.x;
    for (int i = tid; i < 4096; i += 256) {
        int k = i >> 6, n = i & 63, ix = widx(k, n);
        sL[ix] = (short)f2bf(linW[i]);
        sI[ix] = (short)f2bf(interW[i]);
        sW[ix] = (short)f2bf(attW[i]);
    }
    if (tid < 64) {
        sBias[tid] = linb[tid] + interb[tid];
        sAttb[tid] = attb[tid];
        sAvec[tid] = avec[tid];
    }
    __syncthreads();

    const bf16x8* pL = (const bf16x8*)sL;
    const bf16x8* pI = (const bf16x8*)sI;
    const bf16x8* pW = (const bf16x8*)sW;

    int lane = tid & 63;
    int wv = tid >> 6;
    int nl = lane & 15;
    int q  = lane >> 4;
    float* myH = sH + wv * (16 * 65);
    int gw = blockIdx.x * 4 + wv;
    int nw = gridDim.x * 4;
    float att_acc = 0.f;

    for (int c = gw; c < NCHUNK; c += nw) {
        int r0 = c * 16;
        const bf16x8* gp = (const bf16x8*)(G + (size_t)(r0 + nl) * 128);
        bf16x8 Ah[2], Qh[2];
        Ah[0] = gp[q];         Ah[1] = gp[4 + q];
        Qh[0] = gp[8 + q];     Qh[1] = gp[12 + q];
        #pragma unroll
        for (int nt = 0; nt < 4; ++nt) {
            float b = sBias[nt * 16 + nl];
            f32x4 acc = {b, b, b, b};
            #pragma unroll
            for (int kh = 0; kh < 2; ++kh) {
                int f = ((nt * 2 + kh) * 4 + q) * 16 + nl;
                acc = __builtin_amdgcn_mfma_f32_16x16x32_bf16(Ah[kh], pL[f], acc, 0, 0, 0);
                acc = __builtin_amdgcn_mfma_f32_16x16x32_bf16(Qh[kh], pI[f], acc, 0, 0, 0);
            }
            #pragma unroll
            for (int reg = 0; reg < 4; ++reg) {
                int row = q * 4 + reg;
                Hout[(size_t)(r0 + row) * 64 + nt * 16 + nl] = f2bf(acc[reg]);
                myH[row * 65 + nt * 16 + nl] = acc[reg];
            }
        }
        // attention
        bf16x8 Th[2];
        #pragma unroll
        for (int kh = 0; kh < 2; ++kh) {
            #pragma unroll
            for (int j = 0; j < 8; ++j)
                Th[kh][j] = (short)f2bf(myH[nl * 65 + kh * 32 + q * 8 + j]);
        }
        #pragma unroll
        for (int nt = 0; nt < 4; ++nt) {
            float b = sAttb[nt * 16 + nl];
            f32x4 acc = {b, b, b, b};
            #pragma unroll
            for (int kh = 0; kh < 2; ++kh) {
                int f = ((nt * 2 + kh) * 4 + q) * 16 + nl;
                acc = __builtin_amdgcn_mfma_f32_16x16x32_bf16(Th[kh], pW[f], acc, 0, 0, 0);
            }
            float av = sAvec[nt * 16 + nl];
            #pragma unroll
            for (int reg = 0; reg < 4; ++reg)
                att_acc += tanh_fast(acc[reg]) * av;
        }
    }
    #pragma unroll
    for (int o = 32; o >= 1; o >>= 1) att_acc += __shfl_xor(att_acc, o);
    if (lane == 0) atomicAdd(attsum, att_acc);
}

// ---------------------------------------------------------------------------
// beta = softmax(attsum/NN); x = b0*hM + b1*hA + b2*hT (bf16 in, plain loads
// — H is L2-resident from dense); XB = bf16(x) (skipped on last layer);
// fs = (fs + x) * scale
__global__ __launch_bounds__(256) void combine_kernel(
    const ushort4* __restrict__ hM, const ushort4* __restrict__ hA,
    const ushort4* __restrict__ hT, const float* __restrict__ attsum,
    ushort4* __restrict__ XB, float4* __restrict__ fs, float scale, int doXB)
{
    float w0 = attsum[0] * (1.f / NN);
    float w1 = attsum[1] * (1.f / NN);
    float w2 = attsum[2] * (1.f / NN);
    float m = fmaxf(w0, fmaxf(w1, w2));
    float e0 = __expf(w0 - m), e1 = __expf(w1 - m), e2 = __expf(w2 - m);
    float inv = 1.f / (e0 + e1 + e2);
    float b0 = e0 * inv, b1 = e1 * inv, b2 = e2 * inv;

    int i = blockIdx.x * 256 + threadIdx.x;
    if (i >= ND4) return;
    ushort4 um = hM[i], ua = hA[i], ut = hT[i];
    float4 x;
    x.x = b0 * bf2f(um.x) + b1 * bf2f(ua.x) + b2 * bf2f(ut.x);
    x.y = b0 * bf2f(um.y) + b1 * bf2f(ua.y) + b2 * bf2f(ut.y);
    x.z = b0 * bf2f(um.z) + b1 * bf2f(ua.z) + b2 * bf2f(ut.z);
    x.w = b0 * bf2f(um.w) + b1 * bf2f(ua.w) + b2 * bf2f(ut.w);
    if (doXB) {
        ushort4 bo;
        bo.x = f2bf(x.x); bo.y = f2bf(x.y); bo.z = f2bf(x.z); bo.w = f2bf(x.w);
        XB[i] = bo;
    }
    float4 f = fs[i];
    f.x = (f.x + x.x) * scale;
    f.y = (f.y + x.y) * scale;
    f.z = (f.z + x.z) * scale;
    f.w = (f.w + x.w) * scale;
    fs[i] = f;
}

// ---------------------------------------------------------------------------
__global__ __launch_bounds__(256) void mlp_kernel(
    const int* __restrict__ userIdx, const int* __restrict__ itemIdx,
    const float* __restrict__ fin,
    const float* __restrict__ W1, const float* __restrict__ b1,
    const float* __restrict__ W2, const float* __restrict__ b2,
    const float* __restrict__ W3, const float* __restrict__ b3,
    float* __restrict__ pred, float* __restrict__ userE, float* __restrict__ itemE)
{
    __shared__ float sW1[128 * 64];
    __shared__ float sW2[64 * 32];
    __shared__ float sW3[32];
    __shared__ float sb1[64];
    __shared__ float sb2[32];
    int tid = threadIdx.x;
    for (int i = tid; i < 8192; i += 256) sW1[i] = W1[i];
    for (int i = tid; i < 2048; i += 256) sW2[i] = W2[i];
    if (tid < 32) sW3[tid] = W3[tid];
    if (tid < 64) sb1[tid] = b1[tid];
    if (tid < 32) sb2[tid] = b2[tid];
    __syncthreads();
    float bb3 = b3[0];

    int lane = tid & 63;
    int gw = blockIdx.x * 4 + (tid >> 6);
    int nw = gridDim.x * 4;
    for (int p = gw; p < BB; p += nw) {
        int u = userIdx[p];
        int it = itemIdx[p] + N_USER;
        float ue = fin[u * 64 + lane];
        float ie = fin[it * 64 + lane];
        userE[p * 64 + lane] = ue;
        itemE[p * 64 + lane] = ie;
        float h = sb1[lane];
        #pragma unroll
        for (int k = 0; k < 64; ++k) h = fmaf(bcast(ue, k), sW1[k * 64 + lane], h);
        #pragma unroll
        for (int k = 0; k < 64; ++k) h = fmaf(bcast(ie, k), sW1[(k + 64) * 64 + lane], h);
        h = fmaxf(h, 0.f);
        float h2 = sb2[lane & 31];
        #pragma unroll
        for (int k = 0; k < 64; ++k) h2 = fmaf(bcast(h, k), sW2[k * 32 + (lane & 31)], h2);
        float c = (lane < 32) ? h2 * sW3[lane] : 0.f;
        #pragma unroll
        for (int o = 32; o >= 1; o >>= 1) c += __shfl_xor(c, o);
        if (lane == 0) pred[p] = c + bb3;
    }
}

// ---------------------------------------------------------------------------
extern "C" void kernel_launch(void* const* d_in, const int* in_sizes, int n_in,
                              void* d_out, int out_size, void* d_ws, size_t ws_size,
                              hipStream_t stream)
{
    const int*   userIdx = (const int*)d_in[0];
    const int*   itemIdx = (const int*)d_in[1];
    const float* uEmbd   = (const float*)d_in[2];
    const float* iEmbd   = (const float*)d_in[3];
    // slab order: 0 = lap(main), 1 = add, 2 = trust (matches softmax order)
    const int*   e_row[3] = {(const int*)d_in[4],  (const int*)d_in[10], (const int*)d_in[7]};
    const int*   e_col[3] = {(const int*)d_in[5],  (const int*)d_in[11], (const int*)d_in[8]};
    const float* e_val[3] = {(const float*)d_in[6], (const float*)d_in[12], (const float*)d_in[9]};
    const float* lin_W   = (const float*)d_in[13];
    const float* inter_W = (const float*)d_in[14];
    const float* attM_W  = (const float*)d_in[15];
    const float* attA_W  = (const float*)d_in[16];
    const float* attT_W  = (const float*)d_in[17];
    const float* lin_b   = (const float*)d_in[18];
    const float* inter_b = (const float*)d_in[19];
    const float* attM_b  = (const float*)d_in[20];
    const float* attA_b  = (const float*)d_in[21];
    const float* attT_b  = (const float*)d_in[22];
    const float* a_main  = (const float*)d_in[23];
    const float* a_add   = (const float*)d_in[24];
    const float* a_trust = (const float*)d_in[25];
    const float* W1 = (const float*)d_in[26];
    const float* b1 = (const float*)d_in[27];
    const float* W2 = (const float*)d_in[28];
    const float* b2 = (const float*)d_in[29];
    const float* W3 = (const float*)d_in[30];
    const float* b3 = (const float*)d_in[31];

    const float* attWq[3] = {attM_W, attA_W, attT_W};
    const float* attbq[3] = {attM_b, attA_b, attT_b};
    const float* avecq[3] = {a_main, a_add, a_trust};

    // workspace layout (~123 MB, identical to proven round-0 layout):
    // G (bf16 A|S2 interleaved, NN*128 ushorts) | H0,H1,H2 (bf16 ND each) |
    // ECV (3*BUCKTOT int2) | XB (bf16 ND) | RPS,RPE (3*NN ints) | CURS | ATT
    ushort* G  = (ushort*)d_ws;
    ushort* H0 = G + (size_t)NN * 128;
    ushort* H1 = H0 + ND;
    ushort* H2 = H1 + ND;
    int2*   ECV = (int2*)(H2 + ND);
    ushort* XB = (ushort*)(ECV + 3 * (size_t)BUCKTOT);
    int*    RPS = (int*)(XB + ND);
    int*    RPE = RPS + 3 * NN;
    int*    CURS = RPE + 3 * NN;
    float*  ATT = (float*)(CURS + 3 * NBUCK);

    ushort* Hs[3] = {H0, H1, H2};

    // d_out layout: pred[B] | userE[B*64] | itemE[B*64] | final[NN*64]
    float* outPred  = (float*)d_out;
    float* outUser  = outPred + BB;
    float* outItem  = outUser + BB * 64;
    float* outFinal = outItem + BB * 64;

    init_kernel<<<6250, 256, 0, stream>>>((const float4*)uEmbd, (const float4*)iEmbd,
                                          XB, (float4*)outFinal, CURS, ATT);
    bin_kernel<<<3 * BINB, 512, 0, stream>>>(
        e_row[0], e_col[0], e_val[0],
        e_row[1], e_col[1], e_val[1],
        e_row[2], e_col[2], e_val[2], CURS, ECV);
    bsort_kernel<<<3 * NBUCK, 512, 0, stream>>>(CURS, ECV, RPS, RPE);

    for (int l = 0; l < 2; ++l) {
        const float* lw = lin_W + l * 4096;
        const float* iw = inter_W + l * 4096;
        const float* lb = lin_b + l * 64;
        const float* ib = inter_b + l * 64;

        for (int q = 0; q < 3; ++q) {
            if (l == 0 && q == 0) {
                // cold dispatch: proven (256,4) throttle
                spmm_kernel<<<3125, 256, 0, stream>>>(
                    RPS + q * NN, RPE + q * NN, ECV + (size_t)q * BUCKTOT, XB, G);
            } else {
                // warm dispatches: (256,8), ECV/XB already L3-resident
                spmm8_kernel<<<3125, 256, 0, stream>>>(
                    RPS + q * NN, RPE + q * NN, ECV + (size_t)q * BUCKTOT, XB, G);
            }
            dense_kernel<<<512, 256, 0, stream>>>(
                G, Hs[q], lw, iw, lb, ib,
                attWq[q] + l * 4096, attbq[q] + l * 64, avecq[q] + l * 64,
                ATT + l * 3 + q);
        }
        combine_kernel<<<6250, 256, 0, stream>>>(
            (const ushort4*)Hs[0], (const ushort4*)Hs[1], (const ushort4*)Hs[2],
            ATT + l * 3, (ushort4*)XB, (float4*)outFinal,
            (l == 1) ? (1.f / 3.f) : 1.f, (l == 0) ? 1 : 0);
    }

    mlp_kernel<<<512, 256, 0, stream>>>(userIdx, itemIdx, outFinal,
                                        W1, b1, W2, b2, W3, b3,
                                        outPred, outUser, outItem);
}